// Round 1
// baseline (614.685 us; speedup 1.0000x reference)
//
#include <hip/hip_runtime.h>
#include <hip/hip_bf16.h>
#include <stdint.h>
#include <stddef.h>

typedef __attribute__((ext_vector_type(8))) short short8;
typedef __attribute__((ext_vector_type(4))) float floatx4;

#define GLDS16(gptr, lptr)                                                         \
  __builtin_amdgcn_global_load_lds(                                                \
      (const __attribute__((address_space(1))) void*)(gptr),                       \
      (__attribute__((address_space(3))) void*)(lptr), 16, 0, 0)

#define MTOT  100352   // 2048*49 tokens, = 392*256
#define KDIM  384
#define NQKV  1152
#define NPROJ 384

static __device__ __forceinline__ unsigned int bfu(float f) {
    __hip_bfloat16 h = __float2bfloat16(f);
    return (unsigned int)*(unsigned short*)&h;
}

// ---------------------------------------------------------------------------
// fp32 -> bf16 convert (4 elems/thread)
// ---------------------------------------------------------------------------
__global__ void cvt_kernel(const float* __restrict__ in,
                           __hip_bfloat16* __restrict__ out, int n4) {
    int i = blockIdx.x * blockDim.x + threadIdx.x;
    if (i >= n4) return;
    float4 v = ((const float4*)in)[i];
    __hip_bfloat16* o = out + (size_t)i * 4;
    o[0] = __float2bfloat16(v.x);
    o[1] = __float2bfloat16(v.y);
    o[2] = __float2bfloat16(v.z);
    o[3] = __float2bfloat16(v.w);
}

// ---------------------------------------------------------------------------
// comb[h][w][row(49)][52]: col<49 -> tbl+mask ; col>=49 -> -1e30
// ---------------------------------------------------------------------------
__global__ void build_bias_kernel(const float* __restrict__ tbl,
                                  const float* __restrict__ mask,
                                  float* __restrict__ comb) {
    int tid = blockIdx.x * 256 + threadIdx.x;
    if (tid >= 12 * 64 * 49 * 52) return;
    int hw = tid / 2548;
    int nm = tid - hw * 2548;
    int row = nm / 52;
    int col = nm - row * 52;
    int h = hw >> 6;
    int w2 = hw & 63;
    float v = -1e30f;
    if (col < 49) {
        int i1 = row / 7, j1 = row - i1 * 7;
        int i2 = col / 7, j2 = col - i2 * 7;
        int ridx = (i1 - i2 + 6) * 13 + (j1 - j2 + 6);
        v = tbl[ridx * 12 + h] + mask[(size_t)w2 * 2401 + row * 49 + col];
    }
    comb[tid] = v;
}

// ---------------------------------------------------------------------------
// C = A(MxK) * B(NxK)^T + bias.  BM=256 x BN=128 tile, BK=64, 512 threads
// (8 waves, 4M x 2N, 64x64 per wave).  Triple-buffered LDS (144 KB), stages
// issued at half-tile granularity (3 x global_load_lds dwordx4 per thread),
// counted s_waitcnt vmcnt(6) (never drained to 0 in steady state), raw
// s_barrier, s_setprio around the MFMA cluster.  2 phases per K-tile (one per
// kk half: 8 ds_read_b128 + 16 MFMA).  XOR col-swizzled LDS: linear LDS dest,
// pre-swizzled global source, swizzled read (both-sides rule).
// Operand-SWAPPED MFMA: acc[i][j] holds C^T tile -> lane l15 = M-row (token),
// quad*4+r = 4 consecutive N-cols -> vectorized epilogue stores.
// EPI==0: bf16 out (q cols scaled by 1/sqrt(32)), uint2 (4xbf16) stores.
// EPI==1: fp32 out, float4 stores.
//
// Pipeline schedule (NT=6 K-tiles, buffers mod 3):
//   prologue: stage T0(H0,H1), T1(H0,H1); vmcnt(6); barrier
//   phase (t,kk2): ds_read 8 frags from buf[t%3]; stage half kk2 of tile t+2
//                  into buf[(t+2)%3]; barrier; 16 MFMA (setprio 1);
//                  [kk2==1: vmcnt(6) if t+2<NT else vmcnt(0) if t+1<NT];
//                  barrier.
// Safety: reads of buf[t%3] are consumed by the MFMAs before the phase-end
// barrier; first overwrite of buf[t%3] is tile t+3's stage, issued after that
// barrier.  vmcnt(6) at tile end leaves exactly tile t+2's 6 loads in flight
// and forces tile t+1 complete.
// ---------------------------------------------------------------------------
#define STAGE_HALF(T, H, BUF)                                                  \
  do {                                                                         \
    const size_t kb_ = (size_t)(T) * 64;                                       \
    GLDS16(Ab + ((size_t)((H) * 128 + srow)) * KDIM + kb_ + sg * 8,            \
           &sA[BUF][((H) * 128 + srow) * 64 + scg * 8]);                       \
    GLDS16(Ab + ((size_t)((H) * 128 + 64 + srow)) * KDIM + kb_ + sg * 8,       \
           &sA[BUF][((H) * 128 + 64 + srow) * 64 + scg * 8]);                  \
    GLDS16(Bb + ((size_t)((H) * 64 + srow)) * KDIM + kb_ + sg * 8,             \
           &sB[BUF][((H) * 64 + srow) * 64 + scg * 8]);                        \
  } while (0)

template <int EPI>
__global__ __launch_bounds__(512, 2) void gemm_bt_kernel(
    const __hip_bfloat16* __restrict__ A, const __hip_bfloat16* __restrict__ B,
    const float* __restrict__ bias, float* __restrict__ Cout,
    __hip_bfloat16* __restrict__ Cbf, int N, int NBN) {
    __shared__ __hip_bfloat16 sA[3][256 * 64];   // 96 KB
    __shared__ __hip_bfloat16 sB[3][128 * 64];   // 48 KB
    const int t = threadIdx.x;
    const int per_chunk = 8 * NBN;
    const int chunk = blockIdx.x / per_chunk;
    const int rr = blockIdx.x - chunk * per_chunk;
    const int bn = rr >> 3;
    const int bm = chunk * 8 + (rr & 7);

    const int lane = t & 63;
    const int w = t >> 6;                 // wave 0..7
    const int wm = w & 3, wn = w >> 2;    // 4M x 2N wave grid
    const int quad = lane >> 4, l15 = lane & 15;
    const int srow = t >> 3;              // 0..63 staging row within a half
    const int scg = t & 7;                // LDS col-group (linear dest)
    const int sg = scg ^ (srow & 7);      // pre-swizzled global col-group
    const int rsw = l15 & 7;              // read-side swizzle

    const __hip_bfloat16* Ab = A + (size_t)bm * 256 * KDIM;
    const __hip_bfloat16* Bb = B + (size_t)bn * 128 * KDIM;

    const floatx4 fzero = {0.f, 0.f, 0.f, 0.f};
    floatx4 acc[4][4];
#pragma unroll
    for (int i = 0; i < 4; ++i)
#pragma unroll
        for (int j = 0; j < 4; ++j) acc[i][j] = fzero;

    // prologue: tiles 0 and 1 fully staged (12 loads/thread)
    STAGE_HALF(0, 0, 0);
    STAGE_HALF(0, 1, 0);
    STAGE_HALF(1, 0, 1);
    STAGE_HALF(1, 1, 1);
    asm volatile("s_waitcnt vmcnt(6)" ::: "memory");  // tile 0 landed
    asm volatile("s_barrier" ::: "memory");

#pragma unroll
    for (int tt = 0; tt < 6; ++tt) {
        const int bufc = tt % 3;
#pragma unroll
        for (int kk2 = 0; kk2 < 2; ++kk2) {
            short8 af[4], bf[4];
            const int cg = ((kk2 * 4 + quad) ^ rsw) * 8;
#pragma unroll
            for (int i = 0; i < 4; ++i)
                af[i] = *(const short8*)&sA[bufc][(wm * 64 + i * 16 + l15) * 64 + cg];
#pragma unroll
            for (int j = 0; j < 4; ++j)
                bf[j] = *(const short8*)&sB[bufc][(wn * 64 + j * 16 + l15) * 64 + cg];
            if (tt + 2 < 6) {
                STAGE_HALF(tt + 2, kk2, (tt + 2) % 3);
            }
            asm volatile("s_barrier" ::: "memory");
            __builtin_amdgcn_s_setprio(1);
#pragma unroll
            for (int i = 0; i < 4; ++i)
#pragma unroll
                for (int j = 0; j < 4; ++j)
                    acc[i][j] = __builtin_amdgcn_mfma_f32_16x16x32_bf16(
                        bf[j], af[i], acc[i][j], 0, 0, 0);  // SWAPPED
            __builtin_amdgcn_s_setprio(0);
            if (kk2 == 1) {
                if (tt + 2 < 6) {
                    asm volatile("s_waitcnt vmcnt(6)" ::: "memory");
                } else if (tt + 1 < 6) {
                    asm volatile("s_waitcnt vmcnt(0)" ::: "memory");
                }
            }
            asm volatile("s_barrier" ::: "memory");
        }
    }

    // epilogue: lane = token row m; quad*4 = first of 4 consecutive cols
    if (EPI == 0) {
        const float scale = 0.17677669529663687f;  // 1/sqrt(32)
#pragma unroll
        for (int i = 0; i < 4; ++i) {
            const int m = bm * 256 + wm * 64 + i * 16 + l15;
#pragma unroll
            for (int j = 0; j < 4; ++j) {
                const int f0 = bn * 128 + wn * 64 + j * 16 + quad * 4;
                const float4 bv = *(const float4*)&bias[f0];
                const float sc = (f0 < 384) ? scale : 1.0f;
                uint2 pk;
                pk.x = bfu((acc[i][j][0] + bv.x) * sc) |
                       (bfu((acc[i][j][1] + bv.y) * sc) << 16);
                pk.y = bfu((acc[i][j][2] + bv.z) * sc) |
                       (bfu((acc[i][j][3] + bv.w) * sc) << 16);
                *(uint2*)&Cbf[(size_t)m * NQKV + f0] = pk;
            }
        }
    } else {
#pragma unroll
        for (int i = 0; i < 4; ++i) {
            const int m = bm * 256 + wm * 64 + i * 16 + l15;
#pragma unroll
            for (int j = 0; j < 4; ++j) {
                const int f0 = bn * 128 + wn * 64 + j * 16 + quad * 4;
                const float4 bv = *(const float4*)&bias[f0];
                float4 o;
                o.x = acc[i][j][0] + bv.x;
                o.y = acc[i][j][1] + bv.y;
                o.z = acc[i][j][2] + bv.z;
                o.w = acc[i][j][3] + bv.w;
                *(float4*)&Cout[(size_t)m * N + f0] = o;
            }
        }
    }
}

// ---------------------------------------------------------------------------
// attention, one wave per (b_, h).  Reads q/k/v from row-major qkv (M x 1152).
// S^T = K*Q^T so softmax rows live in-lane.  V transposed via blocked LDS.
// O computed operand-swapped -> lane = token, 4 consecutive d -> uint2 stores.
// ---------------------------------------------------------------------------
__global__ __launch_bounds__(64) void attn_kernel(
    const __hip_bfloat16* __restrict__ qkv,
    const float* __restrict__ comb,
    __hip_bfloat16* __restrict__ attn_out) {
    __shared__ unsigned short sP[64 * 72];
    __shared__ unsigned short sVB[4][66][8];  // [d>>3][n][d&7]
    const int id = blockIdx.x;
    const int h = id >> 11;
    const int rem = id & 2047;
    const int w = rem >> 5;
    const int b = rem & 31;
    const int b_ = b * 64 + w;
    const int lane = threadIdx.x;
    const int quad = lane >> 4, l15 = lane & 15;
    const short* base = (const short*)qkv + (size_t)b_ * 49 * 1152 + h * 32;

    const floatx4 fzero = {0.f, 0.f, 0.f, 0.f};

    short8 bQ[4], aK[4];
#pragma unroll
    for (int im = 0; im < 4; ++im) {
        int m = im * 16 + l15;
        m = m > 48 ? 48 : m;
        bQ[im] = *(const short8*)(base + (size_t)m * 1152 + quad * 8);
    }
#pragma unroll
    for (int jn = 0; jn < 4; ++jn) {
        int n = jn * 16 + l15;
        n = n > 48 ? 48 : n;
        aK[jn] = *(const short8*)(base + (size_t)n * 1152 + 384 + quad * 8);
    }
    // V rows -> blocked LDS (zero the pad rows to avoid NaN garbage)
    const short8 zero8 = {0, 0, 0, 0, 0, 0, 0, 0};
#pragma unroll
    for (int jn = 0; jn < 4; ++jn) {
        const int n = jn * 16 + l15;
        const int nc = n > 48 ? 48 : n;
        short8 vv = *(const short8*)(base + (size_t)nc * 1152 + 768 + quad * 8);
        if (n > 48) vv = zero8;
        *(short8*)&sVB[quad][n][0] = vv;
    }

    // ST[im][jn][r] = S[m=im*16+l15][n=jn*16+quad*4+r]
    floatx4 ST[4][4];
#pragma unroll
    for (int im = 0; im < 4; ++im)
#pragma unroll
        for (int jn = 0; jn < 4; ++jn)
            ST[im][jn] = __builtin_amdgcn_mfma_f32_16x16x32_bf16(aK[jn], bQ[im],
                                                                 fzero, 0, 0, 0);

    const float* cb = comb + (size_t)(h * 64 + w) * 2548;
#pragma unroll
    for (int im = 0; im < 4; ++im) {
        const int m = im * 16 + l15;
        const int mrow = m > 48 ? 48 : m;
        const float* rp = cb + mrow * 52;
        float v[16];
#pragma unroll
        for (int jn = 0; jn < 3; ++jn) {
            float4 c4 = *(const float4*)(rp + jn * 16 + quad * 4);
            v[jn * 4 + 0] = ST[im][jn][0] + c4.x;
            v[jn * 4 + 1] = ST[im][jn][1] + c4.y;
            v[jn * 4 + 2] = ST[im][jn][2] + c4.z;
            v[jn * 4 + 3] = ST[im][jn][3] + c4.w;
        }
        {
            const float s48 = rp[48];
            v[12] = (quad == 0) ? (ST[im][3][0] + s48) : -1e30f;
            v[13] = -1e30f;
            v[14] = -1e30f;
            v[15] = -1e30f;
        }
        float mx = v[0];
#pragma unroll
        for (int q = 1; q < 16; ++q) mx = fmaxf(mx, v[q]);
        mx = fmaxf(mx, __shfl_xor(mx, 16));
        mx = fmaxf(mx, __shfl_xor(mx, 32));
        float sum = 0.f;
#pragma unroll
        for (int q = 0; q < 16; ++q) {
            v[q] = __expf(v[q] - mx);
            sum += v[q];
        }
        sum += __shfl_xor(sum, 16);
        sum += __shfl_xor(sum, 32);
        const float inv = 1.0f / sum;
#pragma unroll
        for (int jn = 0; jn < 4; ++jn) {
            uint2 pk;
            pk.x = bfu(v[jn * 4 + 0] * inv) | (bfu(v[jn * 4 + 1] * inv) << 16);
            pk.y = bfu(v[jn * 4 + 2] * inv) | (bfu(v[jn * 4 + 3] * inv) << 16);
            *(uint2*)&sP[m * 72 + jn * 16 + quad * 4] = pk;
        }
    }
    __syncthreads();

    short8 aP[4][2];
#pragma unroll
    for (int im = 0; im < 4; ++im)
#pragma unroll
        for (int kk = 0; kk < 2; ++kk)
            aP[im][kk] =
                *(const short8*)&sP[(im * 16 + l15) * 72 + kk * 32 + quad * 8];

    short8 bV[2][2];
#pragma unroll
    for (int jd = 0; jd < 2; ++jd) {
        const int d = jd * 16 + l15;
        const int db = d >> 3, dl = d & 7;
#pragma unroll
        for (int kk = 0; kk < 2; ++kk) {
            short8 tmp;
#pragma unroll
            for (int jj = 0; jj < 8; ++jj)
                tmp[jj] = (short)sVB[db][kk * 32 + quad * 8 + jj][dl];
            bV[jd][kk] = tmp;
        }
    }

    // O^T tiles: row = d (quad*4+r consecutive), col = token m = l15
    floatx4 O[4][2];
#pragma unroll
    for (int im = 0; im < 4; ++im)
#pragma unroll
        for (int jd = 0; jd < 2; ++jd) {
            floatx4 o = __builtin_amdgcn_mfma_f32_16x16x32_bf16(bV[jd][0],
                                                                aP[im][0], fzero,
                                                                0, 0, 0);
            o = __builtin_amdgcn_mfma_f32_16x16x32_bf16(bV[jd][1], aP[im][1], o, 0,
                                                        0, 0);
            O[im][jd] = o;
        }

#pragma unroll
    for (int im = 0; im < 4; ++im) {
        const int m = im * 16 + l15;
        if (m < 49) {
#pragma unroll
            for (int jd = 0; jd < 2; ++jd) {
                uint2 pk;
                pk.x = bfu(O[im][jd][0]) | (bfu(O[im][jd][1]) << 16);
                pk.y = bfu(O[im][jd][2]) | (bfu(O[im][jd][3]) << 16);
                *(uint2*)&attn_out[((size_t)b_ * 49 + m) * 384 + h * 32 +
                                   jd * 16 + quad * 4] = pk;
            }
        }
    }
}

// ---------------------------------------------------------------------------
extern "C" void kernel_launch(void* const* d_in, const int* in_sizes, int n_in,
                              void* d_out, int out_size, void* d_ws,
                              size_t ws_size, hipStream_t stream) {
    (void)in_sizes; (void)n_in; (void)out_size; (void)ws_size;
    const float* x      = (const float*)d_in[0];
    const float* mask   = (const float*)d_in[1];
    const float* qkv_w  = (const float*)d_in[2];
    const float* qkv_b  = (const float*)d_in[3];
    const float* proj_w = (const float*)d_in[4];
    const float* proj_b = (const float*)d_in[5];
    const float* tbl    = (const float*)d_in[6];
    float* out = (float*)d_out;
    char* ws = (char*)d_ws;

    // layout (bytes), total 316,403,712 (<= round-1-proven 316,836,864):
    //   [0, 77070336)          x_bf / attn_out (aliased; x_bf dead after qkv)
    //   [77070336, 84897792)   comb (7,827,456); wq_bf (884,736) aliased at
    //                          start — wq dead before comb is built
    //   [84897792, 85192704)   wp_bf (294,912)
    //   [85192704, 316403712)  qkv_out row-major M x 1152 bf16 (231,211,008)
    __hip_bfloat16* x_bf   = (__hip_bfloat16*)(ws);
    __hip_bfloat16* wq_bf  = (__hip_bfloat16*)(ws + 77070336);
    float*          comb   = (float*)(ws + 77070336);
    __hip_bfloat16* wp_bf  = (__hip_bfloat16*)(ws + 84897792);
    __hip_bfloat16* qkv_o  = (__hip_bfloat16*)(ws + 85192704);
    __hip_bfloat16* attn_o = x_bf;

    cvt_kernel<<<(MTOT * KDIM / 4 + 255) / 256, 256, 0, stream>>>(x, x_bf,
                                                                  MTOT * KDIM / 4);
    cvt_kernel<<<(NQKV * KDIM / 4 + 255) / 256, 256, 0, stream>>>(
        qkv_w, wq_bf, NQKV * KDIM / 4);
    cvt_kernel<<<(NPROJ * KDIM / 4 + 255) / 256, 256, 0, stream>>>(
        proj_w, wp_bf, NPROJ * KDIM / 4);
    // BM=256: 392 m-tiles, chunked 8 m-tiles x all bn for L2 A-reuse
    gemm_bt_kernel<0><<<49 * 8 * 9, 512, 0, stream>>>(x_bf, wq_bf, qkv_b,
                                                      nullptr, qkv_o, NQKV, 9);
    build_bias_kernel<<<(12 * 64 * 49 * 52 + 255) / 256, 256, 0, stream>>>(
        tbl, mask, comb);
    attn_kernel<<<2048 * 12, 64, 0, stream>>>(qkv_o, comb, attn_o);
    gemm_bt_kernel<1><<<49 * 8 * 3, 512, 0, stream>>>(attn_o, wp_bf, proj_b,
                                                      out, nullptr, NPROJ, 3);
}

// Round 3
// 570.700 us; speedup vs baseline: 1.0771x; 1.0771x over previous
//
#include <hip/hip_runtime.h>
#include <hip/hip_bf16.h>
#include <stdint.h>
#include <stddef.h>

typedef __attribute__((ext_vector_type(8))) short short8;
typedef __attribute__((ext_vector_type(4))) float floatx4;

#define GLDS16(gptr, lptr)                                                         \
  __builtin_amdgcn_global_load_lds(                                                \
      (const __attribute__((address_space(1))) void*)(gptr),                       \
      (__attribute__((address_space(3))) void*)(lptr), 16, 0, 0)

#define MTOT  100352   // 2048*49 tokens, = 392*256
#define KDIM  384
#define NQKV  1152
#define NPROJ 384

static __device__ __forceinline__ unsigned int bfu(float f) {
    __hip_bfloat16 h = __float2bfloat16(f);
    return (unsigned int)*(unsigned short*)&h;
}

// ---------------------------------------------------------------------------
// fp32 -> bf16 convert (4 elems/thread)
// ---------------------------------------------------------------------------
__global__ void cvt_kernel(const float* __restrict__ in,
                           __hip_bfloat16* __restrict__ out, int n4) {
    int i = blockIdx.x * blockDim.x + threadIdx.x;
    if (i >= n4) return;
    float4 v = ((const float4*)in)[i];
    __hip_bfloat16* o = out + (size_t)i * 4;
    o[0] = __float2bfloat16(v.x);
    o[1] = __float2bfloat16(v.y);
    o[2] = __float2bfloat16(v.z);
    o[3] = __float2bfloat16(v.w);
}

// ---------------------------------------------------------------------------
// comb[h][w][row(49)][52]: col<49 -> tbl+mask ; col>=49 -> -1e30
// ---------------------------------------------------------------------------
__global__ void build_bias_kernel(const float* __restrict__ tbl,
                                  const float* __restrict__ mask,
                                  float* __restrict__ comb) {
    int tid = blockIdx.x * 256 + threadIdx.x;
    if (tid >= 12 * 64 * 49 * 52) return;
    int hw = tid / 2548;
    int nm = tid - hw * 2548;
    int row = nm / 52;
    int col = nm - row * 52;
    int h = hw >> 6;
    int w2 = hw & 63;
    float v = -1e30f;
    if (col < 49) {
        int i1 = row / 7, j1 = row - i1 * 7;
        int i2 = col / 7, j2 = col - i2 * 7;
        int ridx = (i1 - i2 + 6) * 13 + (j1 - j2 + 6);
        v = tbl[ridx * 12 + h] + mask[(size_t)w2 * 2401 + row * 49 + col];
    }
    comb[tid] = v;
}

// ---------------------------------------------------------------------------
// C = A(MxK) * B(NxK)^T + bias.  BM=256 x BN=128 tile, BK=64, 256 threads
// (4 waves, 2M x 2N, per-wave 128x64 output -> acc[8][4]).  Single 48 KB LDS
// buffer, round-0-proven sync structure: stage -> syncthreads -> 2x{ds_read,
// 32 MFMA} -> syncthreads.  Rationale vs round-0 (128x128, 64x64/wave):
//   - LDS fragment-read bytes per MFMA: 512 -> 341 B (A-frags amortized over
//     2x the N-extent per wave) — LDS BW was the ~40%-MfmaUtil ceiling.
//   - stage-writes per output element: -25% (A staged once per 256 rows).
//   - barriers per unit work: halved.
//   - keeps TLP latency-hiding (2 blocks/CU x 4 waves) instead of round-1's
//     failed 1-block deep pipeline (K=384 = 6 K-tiles: fill/drain ~1/3).
// XOR col-swizzled LDS: linear LDS dest, pre-swizzled global source,
// swizzled read (both-sides rule).
// Operand-SWAPPED MFMA: acc[i][j] holds C^T tile -> lane l15 = M-row (token),
// quad*4+r = 4 consecutive N-cols -> vectorized epilogue stores.
// EPI==0: bf16 out (q cols scaled by 1/sqrt(32)), uint2 (4xbf16) stores.
// EPI==1: fp32 out, float4 stores.
// ---------------------------------------------------------------------------
template <int EPI>
__global__ __launch_bounds__(256, 2) void gemm_bt_kernel(
    const __hip_bfloat16* __restrict__ A, const __hip_bfloat16* __restrict__ B,
    const float* __restrict__ bias, float* __restrict__ Cout,
    __hip_bfloat16* __restrict__ Cbf, int N, int NBN) {
    __shared__ __hip_bfloat16 sA[256 * 64];   // 32 KB
    __shared__ __hip_bfloat16 sB[128 * 64];   // 16 KB
    const int t = threadIdx.x;
    const int per_chunk = 8 * NBN;
    const int chunk = blockIdx.x / per_chunk;
    const int rr = blockIdx.x - chunk * per_chunk;
    const int bn = rr >> 3;
    const int bm = chunk * 8 + (rr & 7);

    const int lane = t & 63;
    const int w = t >> 6;                 // wave 0..3
    const int wm = w & 1, wn = w >> 1;    // 2M x 2N wave grid
    const int quad = lane >> 4, l15 = lane & 15;
    const int srow = t >> 3;              // 0..31 staging row group
    const int scg = t & 7;                // LDS col-group (linear dest)
    const int sg = scg ^ (srow & 7);      // pre-swizzled global col-group
    const int rsw = l15 & 7;              // read-side swizzle

    const __hip_bfloat16* Ab = A + (size_t)bm * 256 * KDIM;
    const __hip_bfloat16* Bb = B + (size_t)bn * 128 * KDIM;

    const floatx4 fzero = {0.f, 0.f, 0.f, 0.f};
    floatx4 acc[8][4];
#pragma unroll
    for (int i = 0; i < 8; ++i)
#pragma unroll
        for (int j = 0; j < 4; ++j) acc[i][j] = fzero;

    for (int kk = 0; kk < KDIM; kk += 64) {
#pragma unroll
        for (int i = 0; i < 8; ++i) {
            const int r0 = srow + i * 32;
            GLDS16(Ab + (size_t)r0 * KDIM + kk + sg * 8, &sA[r0 * 64 + scg * 8]);
        }
#pragma unroll
        for (int i = 0; i < 4; ++i) {
            const int r0 = srow + i * 32;
            GLDS16(Bb + (size_t)r0 * KDIM + kk + sg * 8, &sB[r0 * 64 + scg * 8]);
        }
        __syncthreads();
#pragma unroll
        for (int kk2 = 0; kk2 < 2; ++kk2) {
            short8 af[8], bf[4];
            const int cg = ((kk2 * 4 + quad) ^ rsw) * 8;
#pragma unroll
            for (int i = 0; i < 8; ++i)
                af[i] = *(const short8*)&sA[(wm * 128 + i * 16 + l15) * 64 + cg];
#pragma unroll
            for (int j = 0; j < 4; ++j)
                bf[j] = *(const short8*)&sB[(wn * 64 + j * 16 + l15) * 64 + cg];
#pragma unroll
            for (int i = 0; i < 8; ++i)
#pragma unroll
                for (int j = 0; j < 4; ++j)
                    acc[i][j] = __builtin_amdgcn_mfma_f32_16x16x32_bf16(
                        bf[j], af[i], acc[i][j], 0, 0, 0);  // SWAPPED
        }
        __syncthreads();
    }

    // epilogue: lane = token row m; quad*4 = first of 4 consecutive cols
    if (EPI == 0) {
        const float scale = 0.17677669529663687f;  // 1/sqrt(32)
#pragma unroll
        for (int i = 0; i < 8; ++i) {
            const int m = bm * 256 + wm * 128 + i * 16 + l15;
#pragma unroll
            for (int j = 0; j < 4; ++j) {
                const int f0 = bn * 128 + wn * 64 + j * 16 + quad * 4;
                const float4 bv = *(const float4*)&bias[f0];
                const float sc = (f0 < 384) ? scale : 1.0f;
                uint2 pk;
                pk.x = bfu((acc[i][j][0] + bv.x) * sc) |
                       (bfu((acc[i][j][1] + bv.y) * sc) << 16);
                pk.y = bfu((acc[i][j][2] + bv.z) * sc) |
                       (bfu((acc[i][j][3] + bv.w) * sc) << 16);
                *(uint2*)&Cbf[(size_t)m * NQKV + f0] = pk;
            }
        }
    } else {
#pragma unroll
        for (int i = 0; i < 8; ++i) {
            const int m = bm * 256 + wm * 128 + i * 16 + l15;
#pragma unroll
            for (int j = 0; j < 4; ++j) {
                const int f0 = bn * 128 + wn * 64 + j * 16 + quad * 4;
                const float4 bv = *(const float4*)&bias[f0];
                float4 o;
                o.x = acc[i][j][0] + bv.x;
                o.y = acc[i][j][1] + bv.y;
                o.z = acc[i][j][2] + bv.z;
                o.w = acc[i][j][3] + bv.w;
                *(float4*)&Cout[(size_t)m * N + f0] = o;
            }
        }
    }
}

// ---------------------------------------------------------------------------
// attention, one wave per (b_, h).  Reads q/k/v from row-major qkv (M x 1152).
// S^T = K*Q^T so softmax rows live in-lane.  V transposed via blocked LDS.
// O computed operand-swapped -> lane = token, 4 consecutive d -> uint2 stores.
// ---------------------------------------------------------------------------
__global__ __launch_bounds__(64) void attn_kernel(
    const __hip_bfloat16* __restrict__ qkv,
    const float* __restrict__ comb,
    __hip_bfloat16* __restrict__ attn_out) {
    __shared__ unsigned short sP[64 * 72];
    __shared__ unsigned short sVB[4][66][8];  // [d>>3][n][d&7]
    const int id = blockIdx.x;
    const int h = id >> 11;
    const int rem = id & 2047;
    const int w = rem >> 5;
    const int b = rem & 31;
    const int b_ = b * 64 + w;
    const int lane = threadIdx.x;
    const int quad = lane >> 4, l15 = lane & 15;
    const short* base = (const short*)qkv + (size_t)b_ * 49 * 1152 + h * 32;

    const floatx4 fzero = {0.f, 0.f, 0.f, 0.f};

    short8 bQ[4], aK[4];
#pragma unroll
    for (int im = 0; im < 4; ++im) {
        int m = im * 16 + l15;
        m = m > 48 ? 48 : m;
        bQ[im] = *(const short8*)(base + (size_t)m * 1152 + quad * 8);
    }
#pragma unroll
    for (int jn = 0; jn < 4; ++jn) {
        int n = jn * 16 + l15;
        n = n > 48 ? 48 : n;
        aK[jn] = *(const short8*)(base + (size_t)n * 1152 + 384 + quad * 8);
    }
    // V rows -> blocked LDS (zero the pad rows to avoid NaN garbage)
    const short8 zero8 = {0, 0, 0, 0, 0, 0, 0, 0};
#pragma unroll
    for (int jn = 0; jn < 4; ++jn) {
        const int n = jn * 16 + l15;
        const int nc = n > 48 ? 48 : n;
        short8 vv = *(const short8*)(base + (size_t)nc * 1152 + 768 + quad * 8);
        if (n > 48) vv = zero8;
        *(short8*)&sVB[quad][n][0] = vv;
    }

    // ST[im][jn][r] = S[m=im*16+l15][n=jn*16+quad*4+r]
    floatx4 ST[4][4];
#pragma unroll
    for (int im = 0; im < 4; ++im)
#pragma unroll
        for (int jn = 0; jn < 4; ++jn)
            ST[im][jn] = __builtin_amdgcn_mfma_f32_16x16x32_bf16(aK[jn], bQ[im],
                                                                 fzero, 0, 0, 0);

    const float* cb = comb + (size_t)(h * 64 + w) * 2548;
#pragma unroll
    for (int im = 0; im < 4; ++im) {
        const int m = im * 16 + l15;
        const int mrow = m > 48 ? 48 : m;
        const float* rp = cb + mrow * 52;
        float v[16];
#pragma unroll
        for (int jn = 0; jn < 3; ++jn) {
            float4 c4 = *(const float4*)(rp + jn * 16 + quad * 4);
            v[jn * 4 + 0] = ST[im][jn][0] + c4.x;
            v[jn * 4 + 1] = ST[im][jn][1] + c4.y;
            v[jn * 4 + 2] = ST[im][jn][2] + c4.z;
            v[jn * 4 + 3] = ST[im][jn][3] + c4.w;
        }
        {
            const float s48 = rp[48];
            v[12] = (quad == 0) ? (ST[im][3][0] + s48) : -1e30f;
            v[13] = -1e30f;
            v[14] = -1e30f;
            v[15] = -1e30f;
        }
        float mx = v[0];
#pragma unroll
        for (int q = 1; q < 16; ++q) mx = fmaxf(mx, v[q]);
        mx = fmaxf(mx, __shfl_xor(mx, 16));
        mx = fmaxf(mx, __shfl_xor(mx, 32));
        float sum = 0.f;
#pragma unroll
        for (int q = 0; q < 16; ++q) {
            v[q] = __expf(v[q] - mx);
            sum += v[q];
        }
        sum += __shfl_xor(sum, 16);
        sum += __shfl_xor(sum, 32);
        const float inv = 1.0f / sum;
#pragma unroll
        for (int jn = 0; jn < 4; ++jn) {
            uint2 pk;
            pk.x = bfu(v[jn * 4 + 0] * inv) | (bfu(v[jn * 4 + 1] * inv) << 16);
            pk.y = bfu(v[jn * 4 + 2] * inv) | (bfu(v[jn * 4 + 3] * inv) << 16);
            *(uint2*)&sP[m * 72 + jn * 16 + quad * 4] = pk;
        }
    }
    __syncthreads();

    short8 aP[4][2];
#pragma unroll
    for (int im = 0; im < 4; ++im)
#pragma unroll
        for (int kk = 0; kk < 2; ++kk)
            aP[im][kk] =
                *(const short8*)&sP[(im * 16 + l15) * 72 + kk * 32 + quad * 8];

    short8 bV[2][2];
#pragma unroll
    for (int jd = 0; jd < 2; ++jd) {
        const int d = jd * 16 + l15;
        const int db = d >> 3, dl = d & 7;
#pragma unroll
        for (int kk = 0; kk < 2; ++kk) {
            short8 tmp;
#pragma unroll
            for (int jj = 0; jj < 8; ++jj)
                tmp[jj] = (short)sVB[db][kk * 32 + quad * 8 + jj][dl];
            bV[jd][kk] = tmp;
        }
    }

    // O^T tiles: row = d (quad*4+r consecutive), col = token m = l15
    floatx4 O[4][2];
#pragma unroll
    for (int im = 0; im < 4; ++im)
#pragma unroll
        for (int jd = 0; jd < 2; ++jd) {
            floatx4 o = __builtin_amdgcn_mfma_f32_16x16x32_bf16(bV[jd][0],
                                                                aP[im][0], fzero,
                                                                0, 0, 0);
            o = __builtin_amdgcn_mfma_f32_16x16x32_bf16(bV[jd][1], aP[im][1], o, 0,
                                                        0, 0);
            O[im][jd] = o;
        }

#pragma unroll
    for (int im = 0; im < 4; ++im) {
        const int m = im * 16 + l15;
        if (m < 49) {
#pragma unroll
            for (int jd = 0; jd < 2; ++jd) {
                uint2 pk;
                pk.x = bfu(O[im][jd][0]) | (bfu(O[im][jd][1]) << 16);
                pk.y = bfu(O[im][jd][2]) | (bfu(O[im][jd][3]) << 16);
                *(uint2*)&attn_out[((size_t)b_ * 49 + m) * 384 + h * 32 +
                                   jd * 16 + quad * 4] = pk;
            }
        }
    }
}

// ---------------------------------------------------------------------------
extern "C" void kernel_launch(void* const* d_in, const int* in_sizes, int n_in,
                              void* d_out, int out_size, void* d_ws,
                              size_t ws_size, hipStream_t stream) {
    (void)in_sizes; (void)n_in; (void)out_size; (void)ws_size;
    const float* x      = (const float*)d_in[0];
    const float* mask   = (const float*)d_in[1];
    const float* qkv_w  = (const float*)d_in[2];
    const float* qkv_b  = (const float*)d_in[3];
    const float* proj_w = (const float*)d_in[4];
    const float* proj_b = (const float*)d_in[5];
    const float* tbl    = (const float*)d_in[6];
    float* out = (float*)d_out;
    char* ws = (char*)d_ws;

    // layout (bytes), total 316,403,712:
    //   [0, 77070336)          x_bf / attn_out (aliased; x_bf dead after qkv)
    //   [77070336, 84897792)   comb (7,827,456); wq_bf (884,736) aliased at
    //                          start — wq dead before comb is built
    //   [84897792, 85192704)   wp_bf (294,912)
    //   [85192704, 316403712)  qkv_out row-major M x 1152 bf16 (231,211,008)
    __hip_bfloat16* x_bf   = (__hip_bfloat16*)(ws);
    __hip_bfloat16* wq_bf  = (__hip_bfloat16*)(ws + 77070336);
    float*          comb   = (float*)(ws + 77070336);
    __hip_bfloat16* wp_bf  = (__hip_bfloat16*)(ws + 84897792);
    __hip_bfloat16* qkv_o  = (__hip_bfloat16*)(ws + 85192704);
    __hip_bfloat16* attn_o = x_bf;

    cvt_kernel<<<(MTOT * KDIM / 4 + 255) / 256, 256, 0, stream>>>(x, x_bf,
                                                                  MTOT * KDIM / 4);
    cvt_kernel<<<(NQKV * KDIM / 4 + 255) / 256, 256, 0, stream>>>(
        qkv_w, wq_bf, NQKV * KDIM / 4);
    cvt_kernel<<<(NPROJ * KDIM / 4 + 255) / 256, 256, 0, stream>>>(
        proj_w, wp_bf, NPROJ * KDIM / 4);
    // BM=256: 392 m-tiles, chunked 8 m-tiles x all bn for L2 A-reuse
    gemm_bt_kernel<0><<<49 * 8 * 9, 256, 0, stream>>>(x_bf, wq_bf, qkv_b,
                                                      nullptr, qkv_o, NQKV, 9);
    build_bias_kernel<<<(12 * 64 * 49 * 52 + 255) / 256, 256, 0, stream>>>(
        tbl, mask, comb);
    attn_kernel<<<2048 * 12, 64, 0, stream>>>(qkv_o, comb, attn_o);
    gemm_bt_kernel<1><<<49 * 8 * 3, 256, 0, stream>>>(attn_o, wp_bf, proj_b,
                                                      out, nullptr, NPROJ, 3);
}

// Round 4
// 569.374 us; speedup vs baseline: 1.0796x; 1.0023x over previous
//
#include <hip/hip_runtime.h>
#include <hip/hip_bf16.h>
#include <stdint.h>
#include <stddef.h>

typedef __attribute__((ext_vector_type(8))) short short8;
typedef __attribute__((ext_vector_type(4))) float floatx4;

#define GLDS16(gptr, lptr)                                                         \
  __builtin_amdgcn_global_load_lds(                                                \
      (const __attribute__((address_space(1))) void*)(gptr),                       \
      (__attribute__((address_space(3))) void*)(lptr), 16, 0, 0)

#define MTOT  100352   // 2048*49 tokens, = 784*128
#define KDIM  384
#define NQKV  1152
#define NPROJ 384

static __device__ __forceinline__ unsigned int bfu(float f) {
    __hip_bfloat16 h = __float2bfloat16(f);
    return (unsigned int)*(unsigned short*)&h;
}

// ---------------------------------------------------------------------------
// fp32 -> bf16 convert (4 elems/thread)
// ---------------------------------------------------------------------------
__global__ void cvt_kernel(const float* __restrict__ in,
                           __hip_bfloat16* __restrict__ out, int n4) {
    int i = blockIdx.x * blockDim.x + threadIdx.x;
    if (i >= n4) return;
    float4 v = ((const float4*)in)[i];
    __hip_bfloat16* o = out + (size_t)i * 4;
    o[0] = __float2bfloat16(v.x);
    o[1] = __float2bfloat16(v.y);
    o[2] = __float2bfloat16(v.z);
    o[3] = __float2bfloat16(v.w);
}

// ---------------------------------------------------------------------------
// comb[h][w][row(49)][52]: col<49 -> tbl+mask ; col>=49 -> -1e30
// ---------------------------------------------------------------------------
__global__ void build_bias_kernel(const float* __restrict__ tbl,
                                  const float* __restrict__ mask,
                                  float* __restrict__ comb) {
    int tid = blockIdx.x * 256 + threadIdx.x;
    if (tid >= 12 * 64 * 49 * 52) return;
    int hw = tid / 2548;
    int nm = tid - hw * 2548;
    int row = nm / 52;
    int col = nm - row * 52;
    int h = hw >> 6;
    int w2 = hw & 63;
    float v = -1e30f;
    if (col < 49) {
        int i1 = row / 7, j1 = row - i1 * 7;
        int i2 = col / 7, j2 = col - i2 * 7;
        int ridx = (i1 - i2 + 6) * 13 + (j1 - j2 + 6);
        v = tbl[ridx * 12 + h] + mask[(size_t)w2 * 2401 + row * 49 + col];
    }
    comb[tid] = v;
}

// ---------------------------------------------------------------------------
// C = A(MxK) * B(NxK)^T + bias.  128x128 tile, BK=64, XOR col-swizzled LDS.
// ROUND-0 PROVEN STRUCTURE (restored verbatim): rounds 1/3 showed every
// occupancy-reducing "efficiency" variant (deep pipeline @1 blk/CU, BM=256
// @2 blk/CU) regresses — cross-block TLP at ~4 blocks/CU is what hides the
// vmcnt(0) barrier drain at NT=6.
// Operand-SWAPPED MFMA: acc[i][j] holds C^T tile -> lane l15 = M-row (token),
// quad*4+r = 4 consecutive N-cols -> vectorized epilogue stores.
// EPI==0: bf16 out (q cols scaled by 1/sqrt(32)), uint2 (4xbf16) stores.
// EPI==1: fp32 out, float4 stores.
// ---------------------------------------------------------------------------
template <int EPI>
__global__ __launch_bounds__(256, 4) void gemm_bt_kernel(
    const __hip_bfloat16* __restrict__ A, const __hip_bfloat16* __restrict__ B,
    const float* __restrict__ bias, float* __restrict__ Cout,
    __hip_bfloat16* __restrict__ Cbf, int N, int NBN) {
    __shared__ __hip_bfloat16 sA[128 * 64];
    __shared__ __hip_bfloat16 sB[128 * 64];
    const int t = threadIdx.x;
    const int per_chunk = 16 * NBN;
    const int chunk = blockIdx.x / per_chunk;
    const int rr = blockIdx.x - chunk * per_chunk;
    const int bn = rr >> 4;
    const int bm = chunk * 16 + (rr & 15);

    const int lane = t & 63;
    const int w = t >> 6;
    const int wm = w & 1, wn = w >> 1;
    const int quad = lane >> 4, l15 = lane & 15;
    const int srow = t >> 3;                 // 0..31
    const int scg = t & 7;                   // LDS col-group
    const int sg = scg ^ (srow & 7);         // swizzled global col-group
    const int rsw = l15 & 7;                 // read-side swizzle

    const __hip_bfloat16* Ab = A + (size_t)bm * 128 * KDIM;
    const __hip_bfloat16* Bb = B + (size_t)bn * 128 * KDIM;

    const floatx4 fzero = {0.f, 0.f, 0.f, 0.f};
    floatx4 acc[4][4];
#pragma unroll
    for (int i = 0; i < 4; ++i)
#pragma unroll
        for (int j = 0; j < 4; ++j) acc[i][j] = fzero;

    for (int kk = 0; kk < KDIM; kk += 64) {
#pragma unroll
        for (int i = 0; i < 4; ++i) {
            const int r0 = srow + i * 32;
            GLDS16(Ab + (size_t)r0 * KDIM + kk + sg * 8, &sA[r0 * 64 + scg * 8]);
            GLDS16(Bb + (size_t)r0 * KDIM + kk + sg * 8, &sB[r0 * 64 + scg * 8]);
        }
        __syncthreads();
#pragma unroll
        for (int kk2 = 0; kk2 < 2; ++kk2) {
            short8 af[4], bf[4];
#pragma unroll
            for (int i = 0; i < 4; ++i)
                af[i] = *(const short8*)&sA[(wm * 64 + i * 16 + l15) * 64 +
                                            ((kk2 * 4 + quad) ^ rsw) * 8];
#pragma unroll
            for (int j = 0; j < 4; ++j)
                bf[j] = *(const short8*)&sB[(wn * 64 + j * 16 + l15) * 64 +
                                            ((kk2 * 4 + quad) ^ rsw) * 8];
#pragma unroll
            for (int i = 0; i < 4; ++i)
#pragma unroll
                for (int j = 0; j < 4; ++j)
                    acc[i][j] = __builtin_amdgcn_mfma_f32_16x16x32_bf16(
                        bf[j], af[i], acc[i][j], 0, 0, 0);  // SWAPPED
        }
        __syncthreads();
    }

    // epilogue: lane = token row m; quad*4 = first of 4 consecutive cols
    if (EPI == 0) {
        const float scale = 0.17677669529663687f;  // 1/sqrt(32)
#pragma unroll
        for (int i = 0; i < 4; ++i) {
            const int m = bm * 128 + wm * 64 + i * 16 + l15;
#pragma unroll
            for (int j = 0; j < 4; ++j) {
                const int f0 = bn * 128 + wn * 64 + j * 16 + quad * 4;
                const float4 bv = *(const float4*)&bias[f0];
                const float sc = (f0 < 384) ? scale : 1.0f;
                uint2 pk;
                pk.x = bfu((acc[i][j][0] + bv.x) * sc) |
                       (bfu((acc[i][j][1] + bv.y) * sc) << 16);
                pk.y = bfu((acc[i][j][2] + bv.z) * sc) |
                       (bfu((acc[i][j][3] + bv.w) * sc) << 16);
                *(uint2*)&Cbf[(size_t)m * NQKV + f0] = pk;
            }
        }
    } else {
#pragma unroll
        for (int i = 0; i < 4; ++i) {
            const int m = bm * 128 + wm * 64 + i * 16 + l15;
#pragma unroll
            for (int j = 0; j < 4; ++j) {
                const int f0 = bn * 128 + wn * 64 + j * 16 + quad * 4;
                const float4 bv = *(const float4*)&bias[f0];
                float4 o;
                o.x = acc[i][j][0] + bv.x;
                o.y = acc[i][j][1] + bv.y;
                o.z = acc[i][j][2] + bv.z;
                o.w = acc[i][j][3] + bv.w;
                *(float4*)&Cout[(size_t)m * N + f0] = o;
            }
        }
    }
}

// ---------------------------------------------------------------------------
// attention, one wave per (b_, h).  Reads q/k/v from row-major qkv (M x 1152).
// S^T = K*Q^T so softmax rows live in-lane.  O computed operand-swapped ->
// lane = token, 4 consecutive d -> uint2 stores.
// ROUND-4 CHANGE: sVB (4.2 KB LDS) removed; bV gathered directly from global
// qkv (V[min(n,48)][d] per element — rows n>48 multiply an exactly-zero P,
// expf(-1e30 - mx) underflows to 0, so a clamped finite row is safe).
// Per-WG LDS 13.4 KB -> 9.2 KB: 12 -> 17 workgroups/CU for this 1-wave,
// latency-chain kernel (the TLP lesson from rounds 1/3 applied to attn).
// ---------------------------------------------------------------------------
__global__ __launch_bounds__(64) void attn_kernel(
    const __hip_bfloat16* __restrict__ qkv,
    const float* __restrict__ comb,
    __hip_bfloat16* __restrict__ attn_out) {
    __shared__ unsigned short sP[64 * 72];
    const int id = blockIdx.x;
    const int h = id >> 11;
    const int rem = id & 2047;
    const int w = rem >> 5;
    const int b = rem & 31;
    const int b_ = b * 64 + w;
    const int lane = threadIdx.x;
    const int quad = lane >> 4, l15 = lane & 15;
    const short* base = (const short*)qkv + (size_t)b_ * 49 * 1152 + h * 32;

    const floatx4 fzero = {0.f, 0.f, 0.f, 0.f};

    short8 bQ[4], aK[4];
#pragma unroll
    for (int im = 0; im < 4; ++im) {
        int m = im * 16 + l15;
        m = m > 48 ? 48 : m;
        bQ[im] = *(const short8*)(base + (size_t)m * 1152 + quad * 8);
    }
#pragma unroll
    for (int jn = 0; jn < 4; ++jn) {
        int n = jn * 16 + l15;
        n = n > 48 ? 48 : n;
        aK[jn] = *(const short8*)(base + (size_t)n * 1152 + 384 + quad * 8);
    }

    // ST[im][jn][r] = S[m=im*16+l15][n=jn*16+quad*4+r]
    floatx4 ST[4][4];
#pragma unroll
    for (int im = 0; im < 4; ++im)
#pragma unroll
        for (int jn = 0; jn < 4; ++jn)
            ST[im][jn] = __builtin_amdgcn_mfma_f32_16x16x32_bf16(aK[jn], bQ[im],
                                                                 fzero, 0, 0, 0);

    const float* cb = comb + (size_t)(h * 64 + w) * 2548;
#pragma unroll
    for (int im = 0; im < 4; ++im) {
        const int m = im * 16 + l15;
        const int mrow = m > 48 ? 48 : m;
        const float* rp = cb + mrow * 52;
        float v[16];
#pragma unroll
        for (int jn = 0; jn < 3; ++jn) {
            float4 c4 = *(const float4*)(rp + jn * 16 + quad * 4);
            v[jn * 4 + 0] = ST[im][jn][0] + c4.x;
            v[jn * 4 + 1] = ST[im][jn][1] + c4.y;
            v[jn * 4 + 2] = ST[im][jn][2] + c4.z;
            v[jn * 4 + 3] = ST[im][jn][3] + c4.w;
        }
        {
            const float s48 = rp[48];
            v[12] = (quad == 0) ? (ST[im][3][0] + s48) : -1e30f;
            v[13] = -1e30f;
            v[14] = -1e30f;
            v[15] = -1e30f;
        }
        float mx = v[0];
#pragma unroll
        for (int q = 1; q < 16; ++q) mx = fmaxf(mx, v[q]);
        mx = fmaxf(mx, __shfl_xor(mx, 16));
        mx = fmaxf(mx, __shfl_xor(mx, 32));
        float sum = 0.f;
#pragma unroll
        for (int q = 0; q < 16; ++q) {
            v[q] = __expf(v[q] - mx);
            sum += v[q];
        }
        sum += __shfl_xor(sum, 16);
        sum += __shfl_xor(sum, 32);
        const float inv = 1.0f / sum;
#pragma unroll
        for (int jn = 0; jn < 4; ++jn) {
            uint2 pk;
            pk.x = bfu(v[jn * 4 + 0] * inv) | (bfu(v[jn * 4 + 1] * inv) << 16);
            pk.y = bfu(v[jn * 4 + 2] * inv) | (bfu(v[jn * 4 + 3] * inv) << 16);
            *(uint2*)&sP[m * 72 + jn * 16 + quad * 4] = pk;
        }
    }
    __syncthreads();

    short8 aP[4][2];
#pragma unroll
    for (int im = 0; im < 4; ++im)
#pragma unroll
        for (int kk = 0; kk < 2; ++kk)
            aP[im][kk] =
                *(const short8*)&sP[(im * 16 + l15) * 72 + kk * 32 + quad * 8];

    // bV[jd][kk][jj] = V[n = kk*32 + quad*8 + jj][d = jd*16 + l15], n clamped
    // to 48 (P[n>48] == 0 exactly).  16 same-quad lanes read 32 contiguous
    // bytes per element load -> L2/L3-served gather, no LDS.
    short8 bV[2][2];
#pragma unroll
    for (int jd = 0; jd < 2; ++jd) {
        const int d = jd * 16 + l15;
#pragma unroll
        for (int kk = 0; kk < 2; ++kk) {
            short8 tmp;
#pragma unroll
            for (int jj = 0; jj < 8; ++jj) {
                int n = kk * 32 + quad * 8 + jj;
                n = n > 48 ? 48 : n;
                tmp[jj] = *(base + (size_t)n * 1152 + 768 + d);
            }
            bV[jd][kk] = tmp;
        }
    }

    // O^T tiles: row = d (quad*4+r consecutive), col = token m = l15
    floatx4 O[4][2];
#pragma unroll
    for (int im = 0; im < 4; ++im)
#pragma unroll
        for (int jd = 0; jd < 2; ++jd) {
            floatx4 o = __builtin_amdgcn_mfma_f32_16x16x32_bf16(bV[jd][0],
                                                                aP[im][0], fzero,
                                                                0, 0, 0);
            o = __builtin_amdgcn_mfma_f32_16x16x32_bf16(bV[jd][1], aP[im][1], o, 0,
                                                        0, 0);
            O[im][jd] = o;
        }

#pragma unroll
    for (int im = 0; im < 4; ++im) {
        const int m = im * 16 + l15;
        if (m < 49) {
#pragma unroll
            for (int jd = 0; jd < 2; ++jd) {
                uint2 pk;
                pk.x = bfu(O[im][jd][0]) | (bfu(O[im][jd][1]) << 16);
                pk.y = bfu(O[im][jd][2]) | (bfu(O[im][jd][3]) << 16);
                *(uint2*)&attn_out[((size_t)b_ * 49 + m) * 384 + h * 32 +
                                   jd * 16 + quad * 4] = pk;
            }
        }
    }
}

// ---------------------------------------------------------------------------
extern "C" void kernel_launch(void* const* d_in, const int* in_sizes, int n_in,
                              void* d_out, int out_size, void* d_ws,
                              size_t ws_size, hipStream_t stream) {
    (void)in_sizes; (void)n_in; (void)out_size; (void)ws_size;
    const float* x      = (const float*)d_in[0];
    const float* mask   = (const float*)d_in[1];
    const float* qkv_w  = (const float*)d_in[2];
    const float* qkv_b  = (const float*)d_in[3];
    const float* proj_w = (const float*)d_in[4];
    const float* proj_b = (const float*)d_in[5];
    const float* tbl    = (const float*)d_in[6];
    float* out = (float*)d_out;
    char* ws = (char*)d_ws;

    // layout (bytes), total 316,403,712:
    //   [0, 77070336)          x_bf / attn_out (aliased; x_bf dead after qkv)
    //   [77070336, 84897792)   comb (7,827,456); wq_bf (884,736) aliased at
    //                          start — wq dead before comb is built
    //   [84897792, 85192704)   wp_bf (294,912)
    //   [85192704, 316403712)  qkv_out row-major M x 1152 bf16 (231,211,008)
    __hip_bfloat16* x_bf   = (__hip_bfloat16*)(ws);
    __hip_bfloat16* wq_bf  = (__hip_bfloat16*)(ws + 77070336);
    float*          comb   = (float*)(ws + 77070336);
    __hip_bfloat16* wp_bf  = (__hip_bfloat16*)(ws + 84897792);
    __hip_bfloat16* qkv_o  = (__hip_bfloat16*)(ws + 85192704);
    __hip_bfloat16* attn_o = x_bf;

    cvt_kernel<<<(MTOT * KDIM / 4 + 255) / 256, 256, 0, stream>>>(x, x_bf,
                                                                  MTOT * KDIM / 4);
    cvt_kernel<<<(NQKV * KDIM / 4 + 255) / 256, 256, 0, stream>>>(
        qkv_w, wq_bf, NQKV * KDIM / 4);
    cvt_kernel<<<(NPROJ * KDIM / 4 + 255) / 256, 256, 0, stream>>>(
        proj_w, wp_bf, NPROJ * KDIM / 4);
    gemm_bt_kernel<0><<<784 * 9, 256, 0, stream>>>(x_bf, wq_bf, qkv_b, nullptr,
                                                   qkv_o, NQKV, 9);
    build_bias_kernel<<<(12 * 64 * 49 * 52 + 255) / 256, 256, 0, stream>>>(
        tbl, mask, comb);
    attn_kernel<<<2048 * 12, 64, 0, stream>>>(qkv_o, comb, attn_o);
    gemm_bt_kernel<1><<<784 * 3, 256, 0, stream>>>(attn_o, wp_bf, proj_b, out,
                                                   nullptr, NPROJ, 3);
}

// Round 5
// 567.980 us; speedup vs baseline: 1.0822x; 1.0025x over previous
//
#include <hip/hip_runtime.h>
#include <hip/hip_bf16.h>
#include <stdint.h>
#include <stddef.h>

typedef __attribute__((ext_vector_type(8))) short short8;
typedef __attribute__((ext_vector_type(4))) float floatx4;

#define GLDS16(gptr, lptr)                                                         \
  __builtin_amdgcn_global_load_lds(                                                \
      (const __attribute__((address_space(1))) void*)(gptr),                       \
      (__attribute__((address_space(3))) void*)(lptr), 16, 0, 0)

#define MTOT  100352   // 2048*49 tokens, = 784*128
#define KDIM  384
#define NQKV  1152
#define NPROJ 384

static __device__ __forceinline__ unsigned int bfu(float f) {
    __hip_bfloat16 h = __float2bfloat16(f);
    return (unsigned int)*(unsigned short*)&h;
}

// ---------------------------------------------------------------------------
// merged weight cvt: wq (1152x384) then wp (384x384), fp32 -> bf16,
// float4 in / packed uint2 out.  110592 + 36864 = 147456 float4s = 576 blocks.
// ---------------------------------------------------------------------------
__global__ void cvt2_kernel(const float* __restrict__ wq,
                            const float* __restrict__ wp,
                            __hip_bfloat16* __restrict__ wqo,
                            __hip_bfloat16* __restrict__ wpo) {
    int i = blockIdx.x * 256 + threadIdx.x;
    const float* src;
    __hip_bfloat16* dst;
    int j;
    if (i < 110592) {
        src = wq; dst = wqo; j = i;
    } else {
        src = wp; dst = wpo; j = i - 110592;
    }
    float4 v = ((const float4*)src)[j];
    uint2 p;
    p.x = bfu(v.x) | (bfu(v.y) << 16);
    p.y = bfu(v.z) | (bfu(v.w) << 16);
    *(uint2*)(dst + (size_t)j * 4) = p;
}

// ---------------------------------------------------------------------------
// comb[h][w][row(49)][52]: col<49 -> tbl+mask ; col>=49 -> -1e30
// ---------------------------------------------------------------------------
__global__ void build_bias_kernel(const float* __restrict__ tbl,
                                  const float* __restrict__ mask,
                                  float* __restrict__ comb) {
    int tid = blockIdx.x * 256 + threadIdx.x;
    if (tid >= 12 * 64 * 49 * 52) return;
    int hw = tid / 2548;
    int nm = tid - hw * 2548;
    int row = nm / 52;
    int col = nm - row * 52;
    int h = hw >> 6;
    int w2 = hw & 63;
    float v = -1e30f;
    if (col < 49) {
        int i1 = row / 7, j1 = row - i1 * 7;
        int i2 = col / 7, j2 = col - i2 * 7;
        int ridx = (i1 - i2 + 6) * 13 + (j1 - j2 + 6);
        v = tbl[ridx * 12 + h] + mask[(size_t)w2 * 2401 + row * 49 + col];
    }
    comb[tid] = v;
}

// ---------------------------------------------------------------------------
// C = A(MxK) * B(NxK)^T + bias.  128x128 tile, BK=64, XOR col-swizzled LDS.
// ROUND-0 PROVEN sync structure (stage -> sync -> 2x{ds_read,16 MFMA} -> sync;
// rounds 1/3 proved occupancy-reducing schedule variants regress at NT=6).
// EPI==0 (qkv): A is read DIRECTLY AS FP32 from x — staged f32 into LDS
//   (32 KB A + 16 KB B = 48 KB, still 3 blocks/CU), fragments converted to
//   bf16 in-register (same RNE rounding as the old cvt kernel -> identical
//   numerics).  This deletes the x-cvt dispatch and its 308 MB round-trip.
//   A-swizzle: 16 chunks/row of 16 B; staged chunk c holds global chunk
//   c ^ (row&15); read chunk = g ^ l15 -> 2-way bank aliasing (free).
//   Output bf16 (q cols scaled 1/sqrt(32)), uint2 stores.
// EPI==1 (proj): A bf16 path verbatim from round 0, fp32 out, float4 stores.
// Operand-SWAPPED MFMA: acc[i][j] holds C^T tile -> lane l15 = M-row (token),
// quad*4+r = 4 consecutive N-cols -> vectorized epilogue stores.
// ---------------------------------------------------------------------------
template <int EPI>
__global__ __launch_bounds__(256, EPI == 0 ? 3 : 4) void gemm_bt_kernel(
    const float* __restrict__ Af32, const __hip_bfloat16* __restrict__ Abf,
    const __hip_bfloat16* __restrict__ B, const float* __restrict__ bias,
    float* __restrict__ Cout, __hip_bfloat16* __restrict__ Cbf, int N,
    int NBN) {
    __shared__ __align__(16) char smem[EPI == 0 ? 49152 : 32768];
    __hip_bfloat16* sB = (__hip_bfloat16*)smem;              // 16 KB
    float* sAf = (float*)(smem + 16384);                     // EPI0: 32 KB
    __hip_bfloat16* sA = (__hip_bfloat16*)(smem + 16384);    // EPI1: 16 KB

    const int t = threadIdx.x;
    const int per_chunk = 16 * NBN;
    const int chunk = blockIdx.x / per_chunk;
    const int rr = blockIdx.x - chunk * per_chunk;
    const int bn = rr >> 4;
    const int bm = chunk * 16 + (rr & 15);

    const int lane = t & 63;
    const int w = t >> 6;
    const int wm = w & 1, wn = w >> 1;
    const int quad = lane >> 4, l15 = lane & 15;
    const int srow = t >> 3;                 // 0..31 (B staging)
    const int scg = t & 7;                   // B LDS col-group
    const int sg = scg ^ (srow & 7);         // B swizzled global col-group
    const int rsw = l15 & 7;                 // B read-side swizzle
    // A f32 staging (EPI0): 16 chunks of 16 B per 256-B row
    const int arow0 = t >> 4;                // 0..15
    const int acg = t & 15;                  // LDS chunk (linear dest)
    const int asg = acg ^ arow0;             // pre-swizzled global chunk

    const float* Axb = Af32 + (size_t)bm * 128 * KDIM;
    const __hip_bfloat16* Ab = Abf + (size_t)bm * 128 * KDIM;
    const __hip_bfloat16* Bb = B + (size_t)bn * 128 * KDIM;

    const floatx4 fzero = {0.f, 0.f, 0.f, 0.f};
    floatx4 acc[4][4];
#pragma unroll
    for (int i = 0; i < 4; ++i)
#pragma unroll
        for (int j = 0; j < 4; ++j) acc[i][j] = fzero;

    for (int kk = 0; kk < KDIM; kk += 64) {
        if (EPI == 0) {
#pragma unroll
            for (int i = 0; i < 8; ++i) {
                const int r0 = arow0 + i * 16;
                GLDS16(Axb + (size_t)r0 * KDIM + kk + asg * 4,
                       &sAf[r0 * 64 + acg * 4]);
            }
        } else {
#pragma unroll
            for (int i = 0; i < 4; ++i) {
                const int r0 = srow + i * 32;
                GLDS16(Ab + (size_t)r0 * KDIM + kk + sg * 8,
                       &sA[r0 * 64 + scg * 8]);
            }
        }
#pragma unroll
        for (int i = 0; i < 4; ++i) {
            const int r0 = srow + i * 32;
            GLDS16(Bb + (size_t)r0 * KDIM + kk + sg * 8, &sB[r0 * 64 + scg * 8]);
        }
        __syncthreads();
#pragma unroll
        for (int kk2 = 0; kk2 < 2; ++kk2) {
            short8 af[4], bf[4];
            if (EPI == 0) {
#pragma unroll
                for (int i = 0; i < 4; ++i) {
                    const int arow = wm * 64 + i * 16 + l15;
                    const int c0 = kk2 * 8 + quad * 2;
                    const float4 fa =
                        *(const float4*)&sAf[arow * 64 + (c0 ^ l15) * 4];
                    const float4 fb =
                        *(const float4*)&sAf[arow * 64 + ((c0 + 1) ^ l15) * 4];
                    short8 a;
                    a[0] = (short)bfu(fa.x);
                    a[1] = (short)bfu(fa.y);
                    a[2] = (short)bfu(fa.z);
                    a[3] = (short)bfu(fa.w);
                    a[4] = (short)bfu(fb.x);
                    a[5] = (short)bfu(fb.y);
                    a[6] = (short)bfu(fb.z);
                    a[7] = (short)bfu(fb.w);
                    af[i] = a;
                }
            } else {
#pragma unroll
                for (int i = 0; i < 4; ++i)
                    af[i] = *(const short8*)&sA[(wm * 64 + i * 16 + l15) * 64 +
                                                ((kk2 * 4 + quad) ^ rsw) * 8];
            }
#pragma unroll
            for (int j = 0; j < 4; ++j)
                bf[j] = *(const short8*)&sB[(wn * 64 + j * 16 + l15) * 64 +
                                            ((kk2 * 4 + quad) ^ rsw) * 8];
#pragma unroll
            for (int i = 0; i < 4; ++i)
#pragma unroll
                for (int j = 0; j < 4; ++j)
                    acc[i][j] = __builtin_amdgcn_mfma_f32_16x16x32_bf16(
                        bf[j], af[i], acc[i][j], 0, 0, 0);  // SWAPPED
        }
        __syncthreads();
    }

    // epilogue: lane = token row m; quad*4 = first of 4 consecutive cols
    if (EPI == 0) {
        const float scale = 0.17677669529663687f;  // 1/sqrt(32)
#pragma unroll
        for (int i = 0; i < 4; ++i) {
            const int m = bm * 128 + wm * 64 + i * 16 + l15;
#pragma unroll
            for (int j = 0; j < 4; ++j) {
                const int f0 = bn * 128 + wn * 64 + j * 16 + quad * 4;
                const float4 bv = *(const float4*)&bias[f0];
                const float sc = (f0 < 384) ? scale : 1.0f;
                uint2 pk;
                pk.x = bfu((acc[i][j][0] + bv.x) * sc) |
                       (bfu((acc[i][j][1] + bv.y) * sc) << 16);
                pk.y = bfu((acc[i][j][2] + bv.z) * sc) |
                       (bfu((acc[i][j][3] + bv.w) * sc) << 16);
                *(uint2*)&Cbf[(size_t)m * NQKV + f0] = pk;
            }
        }
    } else {
#pragma unroll
        for (int i = 0; i < 4; ++i) {
            const int m = bm * 128 + wm * 64 + i * 16 + l15;
#pragma unroll
            for (int j = 0; j < 4; ++j) {
                const int f0 = bn * 128 + wn * 64 + j * 16 + quad * 4;
                const float4 bv = *(const float4*)&bias[f0];
                float4 o;
                o.x = acc[i][j][0] + bv.x;
                o.y = acc[i][j][1] + bv.y;
                o.z = acc[i][j][2] + bv.z;
                o.w = acc[i][j][3] + bv.w;
                *(float4*)&Cout[(size_t)m * N + f0] = o;
            }
        }
    }
}

// ---------------------------------------------------------------------------
// attention, one wave per (b_, h).  Reads q/k/v from row-major qkv (M x 1152).
// S^T = K*Q^T so softmax rows live in-lane.  V transposed via blocked LDS
// (round-0 best-measured config; the round-4 global V-gather was ~neutral-to-
// worse and is reverted).  O computed operand-swapped -> lane = token,
// 4 consecutive d -> uint2 stores.
// ---------------------------------------------------------------------------
__global__ __launch_bounds__(64) void attn_kernel(
    const __hip_bfloat16* __restrict__ qkv,
    const float* __restrict__ comb,
    __hip_bfloat16* __restrict__ attn_out) {
    __shared__ unsigned short sP[64 * 72];
    __shared__ unsigned short sVB[4][66][8];  // [d>>3][n][d&7]
    const int id = blockIdx.x;
    const int h = id >> 11;
    const int rem = id & 2047;
    const int w = rem >> 5;
    const int b = rem & 31;
    const int b_ = b * 64 + w;
    const int lane = threadIdx.x;
    const int quad = lane >> 4, l15 = lane & 15;
    const short* base = (const short*)qkv + (size_t)b_ * 49 * 1152 + h * 32;

    const floatx4 fzero = {0.f, 0.f, 0.f, 0.f};

    short8 bQ[4], aK[4];
#pragma unroll
    for (int im = 0; im < 4; ++im) {
        int m = im * 16 + l15;
        m = m > 48 ? 48 : m;
        bQ[im] = *(const short8*)(base + (size_t)m * 1152 + quad * 8);
    }
#pragma unroll
    for (int jn = 0; jn < 4; ++jn) {
        int n = jn * 16 + l15;
        n = n > 48 ? 48 : n;
        aK[jn] = *(const short8*)(base + (size_t)n * 1152 + 384 + quad * 8);
    }
    // V rows -> blocked LDS (zero the pad rows to avoid NaN garbage)
    const short8 zero8 = {0, 0, 0, 0, 0, 0, 0, 0};
#pragma unroll
    for (int jn = 0; jn < 4; ++jn) {
        const int n = jn * 16 + l15;
        const int nc = n > 48 ? 48 : n;
        short8 vv = *(const short8*)(base + (size_t)nc * 1152 + 768 + quad * 8);
        if (n > 48) vv = zero8;
        *(short8*)&sVB[quad][n][0] = vv;
    }

    // ST[im][jn][r] = S[m=im*16+l15][n=jn*16+quad*4+r]
    floatx4 ST[4][4];
#pragma unroll
    for (int im = 0; im < 4; ++im)
#pragma unroll
        for (int jn = 0; jn < 4; ++jn)
            ST[im][jn] = __builtin_amdgcn_mfma_f32_16x16x32_bf16(aK[jn], bQ[im],
                                                                 fzero, 0, 0, 0);

    const float* cb = comb + (size_t)(h * 64 + w) * 2548;
#pragma unroll
    for (int im = 0; im < 4; ++im) {
        const int m = im * 16 + l15;
        const int mrow = m > 48 ? 48 : m;
        const float* rp = cb + mrow * 52;
        float v[16];
#pragma unroll
        for (int jn = 0; jn < 3; ++jn) {
            float4 c4 = *(const float4*)(rp + jn * 16 + quad * 4);
            v[jn * 4 + 0] = ST[im][jn][0] + c4.x;
            v[jn * 4 + 1] = ST[im][jn][1] + c4.y;
            v[jn * 4 + 2] = ST[im][jn][2] + c4.z;
            v[jn * 4 + 3] = ST[im][jn][3] + c4.w;
        }
        {
            const float s48 = rp[48];
            v[12] = (quad == 0) ? (ST[im][3][0] + s48) : -1e30f;
            v[13] = -1e30f;
            v[14] = -1e30f;
            v[15] = -1e30f;
        }
        float mx = v[0];
#pragma unroll
        for (int q = 1; q < 16; ++q) mx = fmaxf(mx, v[q]);
        mx = fmaxf(mx, __shfl_xor(mx, 16));
        mx = fmaxf(mx, __shfl_xor(mx, 32));
        float sum = 0.f;
#pragma unroll
        for (int q = 0; q < 16; ++q) {
            v[q] = __expf(v[q] - mx);
            sum += v[q];
        }
        sum += __shfl_xor(sum, 16);
        sum += __shfl_xor(sum, 32);
        const float inv = 1.0f / sum;
#pragma unroll
        for (int jn = 0; jn < 4; ++jn) {
            uint2 pk;
            pk.x = bfu(v[jn * 4 + 0] * inv) | (bfu(v[jn * 4 + 1] * inv) << 16);
            pk.y = bfu(v[jn * 4 + 2] * inv) | (bfu(v[jn * 4 + 3] * inv) << 16);
            *(uint2*)&sP[m * 72 + jn * 16 + quad * 4] = pk;
        }
    }
    __syncthreads();

    short8 aP[4][2];
#pragma unroll
    for (int im = 0; im < 4; ++im)
#pragma unroll
        for (int kk = 0; kk < 2; ++kk)
            aP[im][kk] =
                *(const short8*)&sP[(im * 16 + l15) * 72 + kk * 32 + quad * 8];

    short8 bV[2][2];
#pragma unroll
    for (int jd = 0; jd < 2; ++jd) {
        const int d = jd * 16 + l15;
        const int db = d >> 3, dl = d & 7;
#pragma unroll
        for (int kk = 0; kk < 2; ++kk) {
            short8 tmp;
#pragma unroll
            for (int jj = 0; jj < 8; ++jj)
                tmp[jj] = (short)sVB[db][kk * 32 + quad * 8 + jj][dl];
            bV[jd][kk] = tmp;
        }
    }

    // O^T tiles: row = d (quad*4+r consecutive), col = token m = l15
    floatx4 O[4][2];
#pragma unroll
    for (int im = 0; im < 4; ++im)
#pragma unroll
        for (int jd = 0; jd < 2; ++jd) {
            floatx4 o = __builtin_amdgcn_mfma_f32_16x16x32_bf16(bV[jd][0],
                                                                aP[im][0], fzero,
                                                                0, 0, 0);
            o = __builtin_amdgcn_mfma_f32_16x16x32_bf16(bV[jd][1], aP[im][1], o, 0,
                                                        0, 0);
            O[im][jd] = o;
        }

#pragma unroll
    for (int im = 0; im < 4; ++im) {
        const int m = im * 16 + l15;
        if (m < 49) {
#pragma unroll
            for (int jd = 0; jd < 2; ++jd) {
                uint2 pk;
                pk.x = bfu(O[im][jd][0]) | (bfu(O[im][jd][1]) << 16);
                pk.y = bfu(O[im][jd][2]) | (bfu(O[im][jd][3]) << 16);
                *(uint2*)&attn_out[((size_t)b_ * 49 + m) * 384 + h * 32 +
                                   jd * 16 + quad * 4] = pk;
            }
        }
    }
}

// ---------------------------------------------------------------------------
extern "C" void kernel_launch(void* const* d_in, const int* in_sizes, int n_in,
                              void* d_out, int out_size, void* d_ws,
                              size_t ws_size, hipStream_t stream) {
    (void)in_sizes; (void)n_in; (void)out_size; (void)ws_size;
    const float* x      = (const float*)d_in[0];
    const float* mask   = (const float*)d_in[1];
    const float* qkv_w  = (const float*)d_in[2];
    const float* qkv_b  = (const float*)d_in[3];
    const float* proj_w = (const float*)d_in[4];
    const float* proj_b = (const float*)d_in[5];
    const float* tbl    = (const float*)d_in[6];
    float* out = (float*)d_out;
    char* ws = (char*)d_ws;

    // layout (bytes), total 316,403,712 (<= proven 316,836,864):
    //   [0, 77070336)          attn_out (written by attn, read by proj)
    //   [77070336, 84897792)   comb (7,827,456); wq_bf (884,736) aliased at
    //                          start — wq dead (qkv GEMM done) before comb
    //                          is built
    //   [84897792, 85192704)   wp_bf (294,912)
    //   [85192704, 316403712)  qkv_out row-major M x 1152 bf16 (231,211,008)
    // x_bf is GONE: qkv GEMM reads x fp32 directly.
    __hip_bfloat16* wq_bf  = (__hip_bfloat16*)(ws + 77070336);
    float*          comb   = (float*)(ws + 77070336);
    __hip_bfloat16* wp_bf  = (__hip_bfloat16*)(ws + 84897792);
    __hip_bfloat16* qkv_o  = (__hip_bfloat16*)(ws + 85192704);
    __hip_bfloat16* attn_o = (__hip_bfloat16*)(ws);

    cvt2_kernel<<<576, 256, 0, stream>>>(qkv_w, proj_w, wq_bf, wp_bf);
    gemm_bt_kernel<0><<<784 * 9, 256, 0, stream>>>(x, nullptr, wq_bf, qkv_b,
                                                   nullptr, qkv_o, NQKV, 9);
    build_bias_kernel<<<(12 * 64 * 49 * 52 + 255) / 256, 256, 0, stream>>>(
        tbl, mask, comb);
    attn_kernel<<<2048 * 12, 64, 0, stream>>>(qkv_o, comb, attn_o);
    gemm_bt_kernel<1><<<784 * 3, 256, 0, stream>>>(nullptr, attn_o, wp_bf,
                                                   proj_b, out, nullptr, NPROJ,
                                                   3);
}